// Round 1
// baseline (240.916 us; speedup 1.0000x reference)
//
#include <hip/hip_runtime.h>
#include <hip/hip_bf16.h>
#include <cmath>

// DBRX router: logits = x[16384,6144] @ W[6144,16]; softmax; top-4; L1-normalize.
// Outputs flat: weights fp32[16384*16] | top_weights fp32[16384*4] | experts(as float)[16384*4]

namespace {
constexpr int TOKENS = 16384;
constexpr int DIM    = 6144;
constexpr int NE     = 16;
constexpr int TOPK   = 4;
constexpr int T_TILE = 64;                 // tokens per wave (lane = token)
constexpr int DC     = 32;                 // d-chunk staged per iteration
constexpr int PAD    = 65;                 // LDS row stride (floats) -> <=2-way bank alias
constexpr int TOPW_OFF = TOKENS * NE;      // 262144
constexpr int EXP_OFF  = TOPW_OFF + TOKENS * TOPK; // 327680
}

// ---------------- Phase 1: partial logits, K split across KSLICES ----------------
template <int KSLICES>
__global__ __launch_bounds__(256, 2) void router_partial_kernel(
    const float* __restrict__ x, const float* __restrict__ W,
    float* __restrict__ partial)
{
    constexpr int KS     = DIM / KSLICES;  // d per wave
    constexpr int NCHUNK = KS / DC;

    __shared__ float lds[4][DC][PAD];      // per-wave transposed x tile [d][token]

    const int lane = threadIdx.x & 63;
    const int wv   = threadIdx.x >> 6;
    const int gid  = blockIdx.x * 4 + wv;          // global wave id
    const int tile  = gid / KSLICES;               // 0..255
    const int slice = gid % KSLICES;               // 0..KSLICES-1
    const int t0 = tile * T_TILE;
    const int d0 = slice * KS;
    const int m  = lane & 7;                        // 16-float segment within 32-d row chunk
    const int r0 = lane >> 3;                       // token row base (0..7)

    float acc[NE];
#pragma unroll
    for (int e = 0; e < NE; ++e) acc[e] = 0.f;

    for (int c = 0; c < NCHUNK; ++c) {
        const int db = d0 + c * DC;
        // coalesced load: 8 lanes cover one full 128B line of a token row
        float4 v[8];
#pragma unroll
        for (int it = 0; it < 8; ++it) {
            const int r = r0 + it * 8;
            v[it] = *reinterpret_cast<const float4*>(
                x + (size_t)(t0 + r) * DIM + db + m * 4);
        }
        __syncthreads();  // WAR: previous chunk's reads done before overwrite
#pragma unroll
        for (int it = 0; it < 8; ++it) {
            const int r = r0 + it * 8;
            const int d = m * 4;
            lds[wv][d + 0][r] = v[it].x;
            lds[wv][d + 1][r] = v[it].y;
            lds[wv][d + 2][r] = v[it].z;
            lds[wv][d + 3][r] = v[it].w;
        }
        __syncthreads();  // RAW: writes visible before reads
        const float* wp = W + (size_t)db * NE;
#pragma unroll 4
        for (int dd = 0; dd < DC; ++dd) {
            const float xv = lds[wv][dd][lane];     // stride-1 across lanes: conflict-free
            // wave-uniform address: candidate for s_load; else 4x broadcast dwordx4
            const float4 w0 = *reinterpret_cast<const float4*>(wp + dd * NE + 0);
            const float4 w1 = *reinterpret_cast<const float4*>(wp + dd * NE + 4);
            const float4 w2 = *reinterpret_cast<const float4*>(wp + dd * NE + 8);
            const float4 w3 = *reinterpret_cast<const float4*>(wp + dd * NE + 12);
            acc[0]  = fmaf(xv, w0.x, acc[0]);
            acc[1]  = fmaf(xv, w0.y, acc[1]);
            acc[2]  = fmaf(xv, w0.z, acc[2]);
            acc[3]  = fmaf(xv, w0.w, acc[3]);
            acc[4]  = fmaf(xv, w1.x, acc[4]);
            acc[5]  = fmaf(xv, w1.y, acc[5]);
            acc[6]  = fmaf(xv, w1.z, acc[6]);
            acc[7]  = fmaf(xv, w1.w, acc[7]);
            acc[8]  = fmaf(xv, w2.x, acc[8]);
            acc[9]  = fmaf(xv, w2.y, acc[9]);
            acc[10] = fmaf(xv, w2.z, acc[10]);
            acc[11] = fmaf(xv, w2.w, acc[11]);
            acc[12] = fmaf(xv, w3.x, acc[12]);
            acc[13] = fmaf(xv, w3.y, acc[13]);
            acc[14] = fmaf(xv, w3.z, acc[14]);
            acc[15] = fmaf(xv, w3.w, acc[15]);
        }
    }
    // partial[slice][token][e]
    float* p = partial + ((size_t)slice * TOKENS + t0 + lane) * NE;
#pragma unroll
    for (int q = 0; q < 4; ++q) {
        *reinterpret_cast<float4*>(p + q * 4) =
            make_float4(acc[q * 4 + 0], acc[q * 4 + 1], acc[q * 4 + 2], acc[q * 4 + 3]);
    }
}

// ---------------- Phase 2: reduce slices, softmax, top-4, outputs ----------------
template <int KSLICES>
__global__ __launch_bounds__(256) void router_finish_kernel(
    const float* __restrict__ partial, float* __restrict__ out)
{
    const int t = blockIdx.x * 256 + threadIdx.x;   // one token per thread
    float l[NE];
    {
        const float4* p0 = reinterpret_cast<const float4*>(partial + (size_t)t * NE);
        float4 a0 = p0[0], a1 = p0[1], a2 = p0[2], a3 = p0[3];
        for (int s = 1; s < KSLICES; ++s) {
            const float4* q = reinterpret_cast<const float4*>(
                partial + ((size_t)s * TOKENS + t) * NE);
            float4 b0 = q[0], b1 = q[1], b2 = q[2], b3 = q[3];
            a0.x += b0.x; a0.y += b0.y; a0.z += b0.z; a0.w += b0.w;
            a1.x += b1.x; a1.y += b1.y; a1.z += b1.z; a1.w += b1.w;
            a2.x += b2.x; a2.y += b2.y; a2.z += b2.z; a2.w += b2.w;
            a3.x += b3.x; a3.y += b3.y; a3.z += b3.z; a3.w += b3.w;
        }
        l[0]=a0.x; l[1]=a0.y; l[2]=a0.z; l[3]=a0.w;
        l[4]=a1.x; l[5]=a1.y; l[6]=a1.z; l[7]=a1.w;
        l[8]=a2.x; l[9]=a2.y; l[10]=a2.z; l[11]=a2.w;
        l[12]=a3.x; l[13]=a3.y; l[14]=a3.z; l[15]=a3.w;
    }
    // softmax (max-subtracted, like jax.nn.softmax)
    float mx = l[0];
#pragma unroll
    for (int e = 1; e < NE; ++e) mx = fmaxf(mx, l[e]);
    float w[NE];
    float sum = 0.f;
#pragma unroll
    for (int e = 0; e < NE; ++e) { w[e] = expf(l[e] - mx); sum += w[e]; }
    const float inv = 1.f / sum;
#pragma unroll
    for (int e = 0; e < NE; ++e) w[e] *= inv;

    // stable top-4: strict '>' keeps lowest index on ties (matches jax.lax.top_k)
    int   idx[TOPK];
    float tw[TOPK];
    unsigned used = 0;
#pragma unroll
    for (int k = 0; k < TOPK; ++k) {
        float best = -1.f;
        int   bi   = 0;
#pragma unroll
        for (int e = 0; e < NE; ++e) {
            const bool avail = ((used >> e) & 1u) == 0u;
            if (avail && w[e] > best) { best = w[e]; bi = e; }
        }
        used |= (1u << bi);
        idx[k] = bi;
        tw[k]  = best;
    }
    const float s4 = tw[0] + tw[1] + tw[2] + tw[3];  // weights >= 0 -> abs == id
    const float rinv = 1.f / s4;

    // outputs
    float4* o0 = reinterpret_cast<float4*>(out + (size_t)t * NE);
    o0[0] = make_float4(w[0], w[1], w[2], w[3]);
    o0[1] = make_float4(w[4], w[5], w[6], w[7]);
    o0[2] = make_float4(w[8], w[9], w[10], w[11]);
    o0[3] = make_float4(w[12], w[13], w[14], w[15]);
    *reinterpret_cast<float4*>(out + TOPW_OFF + (size_t)t * TOPK) =
        make_float4(tw[0] * rinv, tw[1] * rinv, tw[2] * rinv, tw[3] * rinv);
    *reinterpret_cast<float4*>(out + EXP_OFF + (size_t)t * TOPK) =
        make_float4((float)idx[0], (float)idx[1], (float)idx[2], (float)idx[3]);
}

// ---------------- launch ----------------
template <int KSLICES>
static void launch_impl(const float* x, const float* W, float* out, float* ws,
                        hipStream_t stream)
{
    // waves = 256 tiles * KSLICES; blocks = waves/4
    const int blocks = (256 * KSLICES) / 4;
    router_partial_kernel<KSLICES><<<blocks, 256, 0, stream>>>(x, W, ws);
    router_finish_kernel<KSLICES><<<TOKENS / 256, 256, 0, stream>>>(ws, out);
}

extern "C" void kernel_launch(void* const* d_in, const int* in_sizes, int n_in,
                              void* d_out, int out_size, void* d_ws, size_t ws_size,
                              hipStream_t stream) {
    const float* x = (const float*)d_in[0];
    const float* W = (const float*)d_in[1];
    float* out = (float*)d_out;
    float* ws  = (float*)d_ws;

    const size_t need8 = (size_t)8 * TOKENS * NE * sizeof(float);  // 8 MB
    if (ws_size >= need8) {
        launch_impl<8>(x, W, out, ws, stream);
    } else if (ws_size >= need8 / 2) {
        launch_impl<4>(x, W, out, ws, stream);
    } else if (ws_size >= need8 / 4) {
        launch_impl<2>(x, W, out, ws, stream);
    } else {
        launch_impl<1>(x, W, out, ws, stream);
    }
}

// Round 2
// 113.096 us; speedup vs baseline: 2.1302x; 2.1302x over previous
//
#include <hip/hip_runtime.h>
#include <hip/hip_bf16.h>
#include <cmath>

// DBRX router: logits = x[16384,6144] @ W[6144,16]; softmax; top-4; L1-normalize.
// Outputs flat: weights fp32[16384*16] | top_weights fp32[16384*4] | experts(as float)[16384*4]

namespace {
constexpr int TOKENS = 16384;
constexpr int DIM    = 6144;
constexpr int NE     = 16;
constexpr int TOPK   = 4;
constexpr int T_TILE = 64;                 // tokens per wave (lane = token)
constexpr int DC     = 16;                 // d-chunk per pipeline stage (64B/token-row: full lines)
constexpr int PAD    = 66;                 // token-dim stride -> <=2-way bank alias on writes (free)
constexpr int TOPW_OFF = TOKENS * NE;      // 262144
constexpr int EXP_OFF  = TOPW_OFF + TOKENS * TOPK; // 327680
}

// ---------------- Phase 1: partial logits, K split across KSLICES ----------------
// Block = 4 waves, all on the SAME k-slice (shared W-slice in LDS), different token tiles.
// No in-loop barriers: each wave owns x_lds[wv]; W is read-only after one prologue barrier.
template <int KSLICES>
__global__ __launch_bounds__(256) void router_partial_kernel(
    const float* __restrict__ x, const float* __restrict__ W,
    float* __restrict__ partial)
{
    constexpr int KS     = DIM / KSLICES;  // d per wave
    constexpr int NCHUNK = KS / DC;

    __shared__ float w_lds[KS * NE];       // W slice [KS][16]
    __shared__ float x_lds[4][DC][PAD];    // per-wave transposed x tile [d][token]

    const int lane  = threadIdx.x & 63;
    const int wv    = threadIdx.x >> 6;
    const int slice = blockIdx.x % KSLICES;
    const int tile  = (blockIdx.x / KSLICES) * 4 + wv;   // 0..255
    const int t0 = tile * T_TILE;
    const int d0 = slice * KS;

    // one-time cooperative W-slice stage (coalesced float4)
    {
        const float4* src = reinterpret_cast<const float4*>(W + (size_t)d0 * NE);
        float4* dst = reinterpret_cast<float4*>(w_lds);
        constexpr int NV = KS * NE / 4;
        #pragma unroll
        for (int i = 0; i < NV / 256; ++i) dst[threadIdx.x + i * 256] = src[threadIdx.x + i * 256];
    }
    __syncthreads();   // the ONLY barrier

    const int m  = lane & 3;               // which float4 of the 16-float row chunk
    const int r0 = lane >> 2;              // token row base (0..15)
    const float* xbase = x + (size_t)t0 * DIM + d0 + m * 4;

    float acc[NE];
    #pragma unroll
    for (int e = 0; e < NE; ++e) acc[e] = 0.f;

    float4 v0[4], v1[4], v2[4];
    // prologue: chunks 0 and 1 in flight
    #pragma unroll
    for (int it = 0; it < 4; ++it)
        v0[it] = *reinterpret_cast<const float4*>(xbase + (size_t)(r0 + 16 * it) * DIM);
    #pragma unroll
    for (int it = 0; it < 4; ++it)
        v1[it] = *reinterpret_cast<const float4*>(xbase + (size_t)(r0 + 16 * it) * DIM + DC);

    for (int c = 0; c < NCHUNK; ++c) {
        // write chunk c (regs -> per-wave LDS, transposed). 2-way bank alias max (free).
        #pragma unroll
        for (int it = 0; it < 4; ++it) {
            const int r = r0 + 16 * it;
            const int d = m * 4;
            x_lds[wv][d + 0][r] = v0[it].x;
            x_lds[wv][d + 1][r] = v0[it].y;
            x_lds[wv][d + 2][r] = v0[it].z;
            x_lds[wv][d + 3][r] = v0[it].w;
        }
        // issue chunk c+2 global loads (in flight under this chunk's compute)
        if (c + 2 < NCHUNK) {
            #pragma unroll
            for (int it = 0; it < 4; ++it)
                v2[it] = *reinterpret_cast<const float4*>(
                    xbase + (size_t)(r0 + 16 * it) * DIM + (size_t)(c + 2) * DC);
        }
        // compute chunk c: x from LDS (lane-consecutive, conflict-free),
        // W from LDS at wave-uniform address (broadcast, conflict-free)
        const float* wp = w_lds + (size_t)c * DC * NE;
        #pragma unroll
        for (int dd = 0; dd < DC; ++dd) {
            const float xv = x_lds[wv][dd][lane];
            const float4 w0 = *reinterpret_cast<const float4*>(wp + dd * NE + 0);
            const float4 w1 = *reinterpret_cast<const float4*>(wp + dd * NE + 4);
            const float4 w2 = *reinterpret_cast<const float4*>(wp + dd * NE + 8);
            const float4 w3 = *reinterpret_cast<const float4*>(wp + dd * NE + 12);
            acc[0]  = fmaf(xv, w0.x, acc[0]);
            acc[1]  = fmaf(xv, w0.y, acc[1]);
            acc[2]  = fmaf(xv, w0.z, acc[2]);
            acc[3]  = fmaf(xv, w0.w, acc[3]);
            acc[4]  = fmaf(xv, w1.x, acc[4]);
            acc[5]  = fmaf(xv, w1.y, acc[5]);
            acc[6]  = fmaf(xv, w1.z, acc[6]);
            acc[7]  = fmaf(xv, w1.w, acc[7]);
            acc[8]  = fmaf(xv, w2.x, acc[8]);
            acc[9]  = fmaf(xv, w2.y, acc[9]);
            acc[10] = fmaf(xv, w2.z, acc[10]);
            acc[11] = fmaf(xv, w2.w, acc[11]);
            acc[12] = fmaf(xv, w3.x, acc[12]);
            acc[13] = fmaf(xv, w3.y, acc[13]);
            acc[14] = fmaf(xv, w3.z, acc[14]);
            acc[15] = fmaf(xv, w3.w, acc[15]);
        }
        // rotate pipeline regs (SSA-renamed, no copies)
        #pragma unroll
        for (int it = 0; it < 4; ++it) { v0[it] = v1[it]; v1[it] = v2[it]; }
    }

    // partial[slice][token][e]
    float* p = partial + ((size_t)slice * TOKENS + t0 + lane) * NE;
    #pragma unroll
    for (int q = 0; q < 4; ++q) {
        *reinterpret_cast<float4*>(p + q * 4) =
            make_float4(acc[q * 4 + 0], acc[q * 4 + 1], acc[q * 4 + 2], acc[q * 4 + 3]);
    }
}

// ---------------- Phase 2: reduce slices, softmax, top-4, outputs ----------------
template <int KSLICES>
__global__ __launch_bounds__(256) void router_finish_kernel(
    const float* __restrict__ partial, float* __restrict__ out)
{
    const int t = blockIdx.x * 256 + threadIdx.x;   // one token per thread
    float l[NE];
    {
        const float4* p0 = reinterpret_cast<const float4*>(partial + (size_t)t * NE);
        float4 a0 = p0[0], a1 = p0[1], a2 = p0[2], a3 = p0[3];
        for (int s = 1; s < KSLICES; ++s) {
            const float4* q = reinterpret_cast<const float4*>(
                partial + ((size_t)s * TOKENS + t) * NE);
            float4 b0 = q[0], b1 = q[1], b2 = q[2], b3 = q[3];
            a0.x += b0.x; a0.y += b0.y; a0.z += b0.z; a0.w += b0.w;
            a1.x += b1.x; a1.y += b1.y; a1.z += b1.z; a1.w += b1.w;
            a2.x += b2.x; a2.y += b2.y; a2.z += b2.z; a2.w += b2.w;
            a3.x += b3.x; a3.y += b3.y; a3.z += b3.z; a3.w += b3.w;
        }
        l[0]=a0.x; l[1]=a0.y; l[2]=a0.z; l[3]=a0.w;
        l[4]=a1.x; l[5]=a1.y; l[6]=a1.z; l[7]=a1.w;
        l[8]=a2.x; l[9]=a2.y; l[10]=a2.z; l[11]=a2.w;
        l[12]=a3.x; l[13]=a3.y; l[14]=a3.z; l[15]=a3.w;
    }
    // softmax (max-subtracted, like jax.nn.softmax)
    float mx = l[0];
    #pragma unroll
    for (int e = 1; e < NE; ++e) mx = fmaxf(mx, l[e]);
    float w[NE];
    float sum = 0.f;
    #pragma unroll
    for (int e = 0; e < NE; ++e) { w[e] = expf(l[e] - mx); sum += w[e]; }
    const float inv = 1.f / sum;
    #pragma unroll
    for (int e = 0; e < NE; ++e) w[e] *= inv;

    // stable top-4: strict '>' keeps lowest index on ties (matches jax.lax.top_k)
    int   idx[TOPK];
    float tw[TOPK];
    unsigned used = 0;
    #pragma unroll
    for (int k = 0; k < TOPK; ++k) {
        float best = -1.f;
        int   bi   = 0;
        #pragma unroll
        for (int e = 0; e < NE; ++e) {
            const bool avail = ((used >> e) & 1u) == 0u;
            if (avail && w[e] > best) { best = w[e]; bi = e; }
        }
        used |= (1u << bi);
        idx[k] = bi;
        tw[k]  = best;
    }
    const float s4 = tw[0] + tw[1] + tw[2] + tw[3];  // weights >= 0 -> abs == id
    const float rinv = 1.f / s4;

    // outputs
    float4* o0 = reinterpret_cast<float4*>(out + (size_t)t * NE);
    o0[0] = make_float4(w[0], w[1], w[2], w[3]);
    o0[1] = make_float4(w[4], w[5], w[6], w[7]);
    o0[2] = make_float4(w[8], w[9], w[10], w[11]);
    o0[3] = make_float4(w[12], w[13], w[14], w[15]);
    *reinterpret_cast<float4*>(out + TOPW_OFF + (size_t)t * TOPK) =
        make_float4(tw[0] * rinv, tw[1] * rinv, tw[2] * rinv, tw[3] * rinv);
    *reinterpret_cast<float4*>(out + EXP_OFF + (size_t)t * TOPK) =
        make_float4((float)idx[0], (float)idx[1], (float)idx[2], (float)idx[3]);
}

// ---------------- launch ----------------
template <int KSLICES>
static void launch_impl(const float* x, const float* W, float* out, float* ws,
                        hipStream_t stream)
{
    const int blocks = KSLICES * 64;   // 64 block-groups of 4 token-tiles each
    router_partial_kernel<KSLICES><<<blocks, 256, 0, stream>>>(x, W, ws);
    router_finish_kernel<KSLICES><<<TOKENS / 256, 256, 0, stream>>>(ws, out);
}

extern "C" void kernel_launch(void* const* d_in, const int* in_sizes, int n_in,
                              void* d_out, int out_size, void* d_ws, size_t ws_size,
                              hipStream_t stream) {
    const float* x = (const float*)d_in[0];
    const float* W = (const float*)d_in[1];
    float* out = (float*)d_out;
    float* ws  = (float*)d_ws;

    const size_t per_slice = (size_t)TOKENS * NE * sizeof(float);  // 1 MB
    if (ws_size >= 32 * per_slice) {
        launch_impl<32>(x, W, out, ws, stream);   // 2048 blocks, 29 KB LDS -> 5 blocks/CU
    } else if (ws_size >= 16 * per_slice) {
        launch_impl<16>(x, W, out, ws, stream);   // 1024 blocks, 41 KB LDS -> 3 blocks/CU
    } else if (ws_size >= 8 * per_slice) {
        launch_impl<8>(x, W, out, ws, stream);    // 512 blocks
    } else {
        launch_impl<4>(x, W, out, ws, stream);
    }
}